// Round 13
// baseline (433.143 us; speedup 1.0000x reference)
//
#include <hip/hip_runtime.h>

#define Bq 128
#define Sq 512
#define Cq 37
#define Dq 768
#define VST 40   // vhist row stride in floats

typedef __attribute__((ext_vector_type(2))) float f32x2;

static __device__ __forceinline__ f32x2 pk_fma(f32x2 a, f32x2 b, f32x2 c) {
  f32x2 d; asm("v_pk_fma_f32 %0, %1, %2, %3" : "=v"(d) : "v"(a), "v"(b), "v"(c));
  return d;
}
static __device__ __forceinline__ f32x2 pk_add(f32x2 a, f32x2 b) {
  f32x2 d; asm("v_pk_add_f32 %0, %1, %2" : "=v"(d) : "v"(a), "v"(b));
  return d;
}
static __device__ __forceinline__ float bcast(float v, int p) {
  return __int_as_float(__builtin_amdgcn_ds_bpermute(p << 2, __float_as_int(v)));
}

#define REP18(X) X(0)X(1)X(2)X(3)X(4)X(5)X(6)X(7)X(8)X(9)X(10)X(11)X(12)X(13) \
  X(14)X(15)X(16)X(17)
#define REP37(X) X(0)X(1)X(2)X(3)X(4)X(5)X(6)X(7)X(8)X(9)X(10)X(11)X(12)X(13) \
  X(14)X(15)X(16)X(17)X(18)X(19)X(20)X(21)X(22)X(23)X(24)X(25)X(26)X(27)X(28) \
  X(29)X(30)X(31)X(32)X(33)X(34)X(35)X(36)

// ---------------- Kernel 1: emissions = x @ W + b ----------------
// 256 blocks x 256 thr, 1 token/thread. Per 32-d chunk: x staged COALESCED
// (consecutive lanes read consecutive 16B of a token row) into a TRANSPOSED
// LDS tile xl[d][tok] (pad 257: stores ~2-way, reads 2-way = free); W chunk
// into wl[d][40] (uniform-addr b128 broadcasts). Inner: 37 independent
// v_fmac per d. T14 split: next-chunk global loads issue before compute.
__global__ __launch_bounds__(256) void emis_kernel(
    const float* __restrict__ x, const float* __restrict__ W,
    const float* __restrict__ bias, float* __restrict__ em)
{
  __shared__ float xl[2][32][257];         // 65,792 B
  __shared__ float wl[2][32][40];          // 10,240 B
  int tid = threadIdx.x;
  int tok0 = blockIdx.x * 256;
  float acc[37];
#pragma unroll
  for (int c = 0; c < Cq; ++c) acc[c] = 0.f;

  float4 xv[8]; float wv[5];
#pragma unroll
  for (int r = 0; r < 8; ++r) {            // chunk 0: coalesced x
    int i = r * 256 + tid;
    xv[r] = *(const float4*)(x + (size_t)(tok0 + (i >> 3)) * Dq + (i & 7) * 4);
  }
#pragma unroll
  for (int k = 0; k < 5; ++k) {
    int j = k * 256 + tid;
    wv[k] = (j < 32 * Cq) ? W[j] : 0.f;
  }
#pragma unroll
  for (int r = 0; r < 8; ++r) {            // transpose-store into buf 0
    int i = r * 256 + tid;
    xl[0][(i & 7) * 4 + 0][i >> 3] = xv[r].x;
    xl[0][(i & 7) * 4 + 1][i >> 3] = xv[r].y;
    xl[0][(i & 7) * 4 + 2][i >> 3] = xv[r].z;
    xl[0][(i & 7) * 4 + 3][i >> 3] = xv[r].w;
  }
#pragma unroll
  for (int k = 0; k < 5; ++k) {
    int j = k * 256 + tid;
    if (j < 32 * Cq) wl[0][j / Cq][j % Cq] = wv[k];
  }
  __syncthreads();

  for (int cc = 0; cc < 24; ++cc) {
    int cur = cc & 1;
    int d0n = (cc + 1) * 32;
    if (cc < 23) {                         // issue next-chunk loads EARLY
#pragma unroll
      for (int r = 0; r < 8; ++r) {
        int i = r * 256 + tid;
        xv[r] = *(const float4*)(x + (size_t)(tok0 + (i >> 3)) * Dq + d0n + (i & 7) * 4);
      }
#pragma unroll
      for (int k = 0; k < 5; ++k) {
        int j = k * 256 + tid;
        wv[k] = (j < 32 * Cq) ? W[d0n * Cq + j] : 0.f;
      }
    }
    // compute current chunk (loads above still in flight)
#pragma unroll 8
    for (int d = 0; d < 32; ++d) {
      float xs = xl[cur][d][tid];
      const float* wr = &wl[cur][d][0];
#pragma unroll
      for (int q = 0; q < 10; ++q) {
        float4 w4 = *(const float4*)(wr + q * 4);   // uniform addr -> broadcast
        if (q * 4 + 0 < Cq) acc[q * 4 + 0] += xs * w4.x;
        if (q * 4 + 1 < Cq) acc[q * 4 + 1] += xs * w4.y;
        if (q * 4 + 2 < Cq) acc[q * 4 + 2] += xs * w4.z;
        if (q * 4 + 3 < Cq) acc[q * 4 + 3] += xs * w4.w;
      }
    }
    if (cc < 23) {                         // write-late into the other buffer
      int nb = cur ^ 1;
#pragma unroll
      for (int r = 0; r < 8; ++r) {
        int i = r * 256 + tid;
        xl[nb][(i & 7) * 4 + 0][i >> 3] = xv[r].x;
        xl[nb][(i & 7) * 4 + 1][i >> 3] = xv[r].y;
        xl[nb][(i & 7) * 4 + 2][i >> 3] = xv[r].z;
        xl[nb][(i & 7) * 4 + 3][i >> 3] = xv[r].w;
      }
#pragma unroll
      for (int k = 0; k < 5; ++k) {
        int j = k * 256 + tid;
        if (j < 32 * Cq) wl[nb][j / Cq][j % Cq] = wv[k];
      }
    }
    __syncthreads();
  }
  size_t tok = tok0 + tid;
#pragma unroll
  for (int c = 0; c < Cq; ++c) em[tok * Cq + c] = acc[c] + bias[c];
}

// ---------------- Kernel 2: serial CRF (R11/R12 pk-packed; unchanged) ----------------
__global__ __launch_bounds__(256) void crf_serial_kernel(
    const float* __restrict__ em, const float* __restrict__ startv,
    const float* __restrict__ endv, const float* __restrict__ trans,
    const int* __restrict__ labels, const unsigned char* __restrict__ maskb,
    float* __restrict__ vhist, float* __restrict__ llp,
    int* __restrict__ lenp, int* __restrict__ lastp)
{
  __shared__ float semm[(Sq + 4) * Cq];    // 516 rows: 4 pad rows kill clamps
  __shared__ float sexch[128];
  __shared__ float s_score, s_logZ;
  int b = blockIdx.x;
  int tid = threadIdx.x, wid = tid >> 6, lane = tid & 63;
  int cl = lane < Cq ? lane : Cq - 1;

  int esz4 = (maskb[1] == 0) ? 1 : 0;
  int len = 0;
#pragma unroll
  for (int k = 0; k < 8; ++k) {
    size_t t = (size_t)lane + (size_t)k * 64;
    unsigned char mb = esz4 ? maskb[((size_t)b * Sq + t) * 4] : maskb[(size_t)b * Sq + t];
    len += (mb != 0);
  }
#pragma unroll
  for (int off = 32; off; off >>= 1) len += __shfl_xor(len, off);

  const float4* src4 = (const float4*)(em + (size_t)b * Sq * Cq);
  float4* dst4 = (float4*)semm;
  for (int i = tid; i < (Sq * Cq) / 4; i += 256) dst4[i] = src4[i];
  if (tid < 4 * Cq) semm[Sq * Cq + tid] = 0.f;
  __syncthreads();

  const float L2E = 1.4426950408889634f, LN2 = 0.6931471805599453f;

  if (wid == 0) {
    // ---- forward, exp domain; 18 pk_fma + 1 fma per step ----
    f32x2 E2[18];
#pragma unroll
    for (int i = 0; i < 18; ++i) {
      E2[i].x = exp2f(trans[(2 * i) * Cq + cl] * L2E);
      E2[i].y = exp2f(trans[(2 * i + 1) * Cq + cl] * L2E);
    }
    float E36 = exp2f(trans[36 * Cq + cl] * L2E);
    float* sE = sexch;
    const float4* se4 = (const float4*)sE;
    float a0 = (lane < Cq) ? (startv[cl] + semm[cl]) : -3.0e38f;
    float K0 = bcast(a0, 0);
    float ez = (lane < Cq) ? exp2f((a0 - K0) * L2E) : 0.f;
    int eacc = 0;
    float wA = exp2f(semm[1 * Cq + cl] * L2E), wB = exp2f(semm[2 * Cq + cl] * L2E);
    float wC = exp2f(semm[3 * Cq + cl] * L2E), wD = exp2f(semm[4 * Cq + cl] * L2E);
    for (int t = 1; t < len; ++t) {
      sE[lane] = ez;                                    // ds_write (in-order DS)
      float raw = semm[(t + 4) * Cq + cl];              // pad rows: no clamp
      float4 gv[10];
#pragma unroll
      for (int q = 0; q < 10; ++q) gv[q] = se4[q];      // 10x ds_read_b128 bcast
      int e0 = ((__float_as_int(gv[0].x) >> 23) & 255) - 127;
      float scale = __int_as_float((127 - e0) << 23);   // 2^-e0 exact
      f32x2 sa = {0.f, 0.f}, sb = {0.f, 0.f};
#define FPK(i) { f32x2 g; \
      if ((i) & 1) { g.x = gv[(i) >> 1].z; g.y = gv[(i) >> 1].w; } \
      else         { g.x = gv[(i) >> 1].x; g.y = gv[(i) >> 1].y; } \
      if ((i) & 1) sb = pk_fma(g, E2[i], sb); else sa = pk_fma(g, E2[i], sa); }
      REP18(FPK)
#undef FPK
      float dot = ((sa.x + sb.x) + (sa.y + sb.y)) + gv[9].x * E36;
      float wcur = wA; wA = wB; wB = wC; wC = wD;
      ez = dot * (wcur * scale);
      eacc += e0;
      wD = exp2f(raw * L2E);
    }
    float xv = (lane < Cq) ? LN2 * (log2f(ez) + (float)eacc) + K0 + endv[cl] : -3.0e38f;
    float mm = xv;
#pragma unroll
    for (int off = 32; off; off >>= 1) mm = fmaxf(mm, __shfl_xor(mm, off));
    float es = exp2f((xv - mm) * L2E);
#pragma unroll
    for (int off = 32; off; off >>= 1) es += __shfl_xor(es, off);
    if (lane == 0) s_logZ = mm + log2f(es) * LN2;
  } else if (wid == 1) {
    // ---- viterbi: pk_add (exact) + max3 nests (exact) -> tags identical ----
    f32x2 T2[18];
#pragma unroll
    for (int i = 0; i < 18; ++i) {
      T2[i].x = trans[(2 * i) * Cq + cl];
      T2[i].y = trans[(2 * i + 1) * Cq + cl];
    }
    float T36 = trans[36 * Cq + cl];
    float* sV = sexch + 64;
    const float4* sv4 = (const float4*)sV;
    float v = (lane < Cq) ? (startv[cl] + semm[cl]) : -3.0e38f;
    if (lane < Cq) vhist[((size_t)b * Sq) * VST + cl] = v;
    float emA = semm[1 * Cq + cl], emB = semm[2 * Cq + cl];
    float emC = semm[3 * Cq + cl], emD = semm[4 * Cq + cl];
    for (int t = 1; t < len; ++t) {
      sV[lane] = v;
      float raw = semm[(t + 4) * Cq + cl];
      float4 gv[10];
#pragma unroll
      for (int q = 0; q < 10; ++q) gv[q] = sv4[q];
      float m0 = -3.0e38f, m1 = -3.0e38f, m2 = -3.0e38f, m3 = -3.0e38f;
#define VPK(i) { f32x2 g; \
      if ((i) & 1) { g.x = gv[(i) >> 1].z; g.y = gv[(i) >> 1].w; } \
      else         { g.x = gv[(i) >> 1].x; g.y = gv[(i) >> 1].y; } \
      f32x2 c = pk_add(g, T2[i]); \
      if (((i) & 3) == 0) m0 = fmaxf(fmaxf(m0, c.x), c.y); \
      else if (((i) & 3) == 1) m1 = fmaxf(fmaxf(m1, c.x), c.y); \
      else if (((i) & 3) == 2) m2 = fmaxf(fmaxf(m2, c.x), c.y); \
      else m3 = fmaxf(fmaxf(m3, c.x), c.y); }
      REP18(VPK)
#undef VPK
      float c36 = gv[9].x + T36;
      float best = fmaxf(fmaxf(fmaxf(m0, m1), fmaxf(m2, m3)), c36);
      float emc = emA; emA = emB; emB = emC; emC = emD;
      v = (lane < Cq) ? best + emc : -3.0e38f;
      if (lane < Cq) vhist[((size_t)b * Sq + t) * VST + cl] = v;
      emD = raw;
    }
    float xv = (lane < Cq) ? v + endv[cl] : -3.0e38f;
    int idx = (lane < Cq) ? lane : 1000;
#pragma unroll
    for (int off = 32; off; off >>= 1) {
      float xo = __shfl_xor(xv, off); int io = __shfl_xor(idx, off);
      if (xo > xv || (xo == xv && io < idx)) { xv = xo; idx = io; }
    }
    if (lane == 0) { lastp[b] = idx; lenp[b] = len; }
  } else if (wid == 2) {
    // ---- gold path score ----
    const int* lab = labels + (size_t)b * Sq;
    float sc = 0.f;
#pragma unroll
    for (int k = 0; k < 8; ++k) {
      int t = 1 + lane + k * 64;
      if (t < len) {
        int lp = lab[t - 1], lt = lab[t];
        sc += trans[lp * Cq + lt] + semm[t * Cq + lt];
      }
    }
#pragma unroll
    for (int off = 32; off; off >>= 1) sc += __shfl_xor(sc, off);
    if (lane == 0) {
      int l0 = lab[0], lf = lab[len - 1];
      s_score = sc + startv[l0] + semm[l0] + endv[lf];
    }
  }
  __syncthreads();
  if (tid == 0) llp[b] = s_score - s_logZ;
}

// ---------------- Kernel 3: backpointers (parallel recompute) ----------------
__global__ __launch_bounds__(256) void crf_bp_kernel(
    const float* __restrict__ vhist, const float* __restrict__ trans,
    const int* __restrict__ lenp, unsigned char* __restrict__ bp)
{
  int b = blockIdx.x >> 2, chunk = blockIdx.x & 3;
  int wid = threadIdx.x >> 6, lane = threadIdx.x & 63;
  int cl = lane < Cq ? lane : Cq - 1;
  int len = lenp[b];
#define DECLT(i) float T##i = trans[(i) * Cq + cl];
  REP37(DECLT)
  int tend = 1 + (chunk + 1) * 128; if (tend > len) tend = len;
  int rl9 = lane < VST ? lane : VST - 1;
  for (int t = 1 + chunk * 128 + wid; t < tend; t += 4) {
    float vr = vhist[((size_t)b * Sq + (t - 1)) * VST + rl9];
#define BCASTB(i) float br##i = bcast(vr, (i));
    REP37(BCASTB)
    float best = -3.0e38f; int bi = 0;
#define BARG(i) { float cnd = br##i + T##i; if (cnd > best) { best = cnd; bi = (i); } }
    REP37(BARG)                             // ascending + strict '>' => first-index tie-break
    if (lane < Cq) bp[((size_t)b * VST + cl) * Sq + t] = (unsigned char)bi;
  }
}

// ---------------- Kernel 4: register-resident backtrack ----------------
__global__ __launch_bounds__(64) void crf_back_kernel(
    const unsigned char* __restrict__ bp, const int* __restrict__ lenp,
    const int* __restrict__ lastp, float* __restrict__ outp)
{
  int b = blockIdx.x, lane = threadIdx.x;
  int len = __builtin_amdgcn_readfirstlane(lenp[b]);
  int tag = __builtin_amdgcn_readfirstlane(lastp[b]);
  int row = lane < VST ? lane : VST - 1;
  const uint4* src = (const uint4*)(bp + ((size_t)b * VST + row) * Sq);
  unsigned r[128];
#pragma unroll
  for (int k = 0; k < 32; ++k) {
    uint4 q = src[k];
    r[4 * k] = q.x; r[4 * k + 1] = q.y; r[4 * k + 2] = q.z; r[4 * k + 3] = q.w;
  }
  unsigned vt[8];
#pragma unroll
  for (int j = 0; j < 8; ++j) vt[j] = 0u;
  vt[7] = (lane == 63) ? (unsigned)tag : vt[7];
#pragma unroll
  for (int t = 510; t >= 0; --t) {
    int word = __builtin_amdgcn_readlane((int)r[(t + 1) >> 2], tag);
    int nt = (word >> (((t + 1) & 3) * 8)) & 0xff;
    tag = (t + 1 < len) ? nt : tag;
    vt[t >> 6] = (lane == (t & 63)) ? (unsigned)tag : vt[t >> 6];
  }
#pragma unroll
  for (int j = 0; j < 8; ++j) {
    int t = j * 64 + lane;
    float o = (t < len) ? (float)(int)vt[j] : 36.0f;
    outp[(size_t)b * Sq + t] = o;
  }
}

// ---------------- Kernel 5: reduce ll partials ----------------
__global__ __launch_bounds__(64) void ll_reduce_kernel(
    const float* __restrict__ llp, float* __restrict__ outp)
{
  int lane = threadIdx.x;
  float s = llp[lane] + llp[lane + 64];
#pragma unroll
  for (int off = 32; off; off >>= 1) s += __shfl_xor(s, off);
  if (lane == 0) outp[0] = s;
}

extern "C" void kernel_launch(void* const* d_in, const int* in_sizes, int n_in,
                              void* d_out, int out_size, void* d_ws, size_t ws_size,
                              hipStream_t stream)
{
  const float* x      = (const float*)d_in[0];
  const float* W      = (const float*)d_in[1];
  const float* bias   = (const float*)d_in[2];
  const float* startv = (const float*)d_in[3];
  const float* endv   = (const float*)d_in[4];
  const float* trans  = (const float*)d_in[5];
  const int*   labels = (const int*)d_in[6];
  const unsigned char* maskb = (const unsigned char*)d_in[7];
  float* out = (float*)d_out;

  char* ws = (char*)d_ws;
  float* em            = (float*)(ws);                    // 9,699,328 B
  float* vhist         = (float*)(ws + 9699328);          // 10,485,760 B
  unsigned char* bpbuf = (unsigned char*)(ws + 20185088); // 2,621,440 B
  float* llp           = (float*)(ws + 22806528);
  int*   lenp          = (int*)(ws + 22807552);
  int*   lastp         = (int*)(ws + 22808064);

  emis_kernel<<<256, 256, 0, stream>>>(x, W, bias, em);
  crf_serial_kernel<<<128, 256, 0, stream>>>(em, startv, endv, trans, labels, maskb,
                                             vhist, llp, lenp, lastp);
  crf_bp_kernel<<<512, 256, 0, stream>>>(vhist, trans, lenp, bpbuf);
  crf_back_kernel<<<128, 64, 0, stream>>>(bpbuf, lenp, lastp, out + 1);
  ll_reduce_kernel<<<1, 64, 0, stream>>>(llp, out);
}

// Round 14
// 211.032 us; speedup vs baseline: 2.0525x; 2.0525x over previous
//
#include <hip/hip_runtime.h>

#define Bq 128
#define Sq 512
#define Cq 37
#define Dq 768
#define VST 40   // vhist row stride in floats

typedef __attribute__((ext_vector_type(2))) float f32x2;
typedef __attribute__((ext_vector_type(4))) float f32x4;
typedef __attribute__((ext_vector_type(8))) short bf16x8;   // 8 bf16 in 4 VGPRs

static __device__ __forceinline__ f32x2 pk_fma(f32x2 a, f32x2 b, f32x2 c) {
  f32x2 d; asm("v_pk_fma_f32 %0, %1, %2, %3" : "=v"(d) : "v"(a), "v"(b), "v"(c));
  return d;
}
static __device__ __forceinline__ f32x2 pk_add(f32x2 a, f32x2 b) {
  f32x2 d; asm("v_pk_add_f32 %0, %1, %2" : "=v"(d) : "v"(a), "v"(b));
  return d;
}
static __device__ __forceinline__ float bcast(float v, int p) {
  return __int_as_float(__builtin_amdgcn_ds_bpermute(p << 2, __float_as_int(v)));
}

#define REP18(X) X(0)X(1)X(2)X(3)X(4)X(5)X(6)X(7)X(8)X(9)X(10)X(11)X(12)X(13) \
  X(14)X(15)X(16)X(17)
#define REP37(X) X(0)X(1)X(2)X(3)X(4)X(5)X(6)X(7)X(8)X(9)X(10)X(11)X(12)X(13) \
  X(14)X(15)X(16)X(17)X(18)X(19)X(20)X(21)X(22)X(23)X(24)X(25)X(26)X(27)X(28) \
  X(29)X(30)X(31)X(32)X(33)X(34)X(35)X(36)

// ---------------- Kernel 0: pre-split W into bf16 hi/lo B-fragments ----------------
// Entry i = ((ks*3 + nt)*64 + lane)*8 + j  ->  B[k = ks*32 + (lane>>4)*8 + j]
// [c = nt*16 + (lane&15)], zero-padded for c >= 37.
__global__ __launch_bounds__(256) void prep_kernel(
    const float* __restrict__ W, unsigned short* __restrict__ Wbh,
    unsigned short* __restrict__ Wbl)
{
  int i = blockIdx.x * 256 + threadIdx.x;
  if (i >= 24 * 3 * 64 * 8) return;
  int ks = i / 1536, rem = i % 1536;
  int nt = rem / 512, rem2 = rem % 512;
  int lane = rem2 >> 3, j = rem2 & 7;
  int k = ks * 32 + (lane >> 4) * 8 + j;
  int c = nt * 16 + (lane & 15);
  float w = (c < Cq) ? W[(size_t)k * Cq + c] : 0.f;
  unsigned u = __float_as_uint(w);
  unsigned short h = (unsigned short)(u >> 16);          // truncate -> hi bf16
  float hr = __uint_as_float((unsigned)h << 16);
  float r = w - hr;                                      // exact residual
  Wbh[i] = h;
  Wbl[i] = (unsigned short)(__float_as_uint(r) >> 16);   // lo bf16
}

// ---------------- Kernel 1: emissions = x @ W + b via MFMA (bf16 hi/lo split) ----
// Wave = 16-token M-tile x 48 classes (3 N-tiles). Per k-step (K=32):
// 2 coalesced float4 x-loads -> split to Ah/Al; 6 coalesced B-frag loads;
// 9 x mfma_f32_16x16x32_bf16 (xh*wh + xh*wl + xl*wh).
__global__ __launch_bounds__(256) void emis_kernel(
    const float* __restrict__ x, const unsigned short* __restrict__ Wbh,
    const unsigned short* __restrict__ Wbl, const float* __restrict__ bias,
    float* __restrict__ em)
{
  int tid = threadIdx.x, lane = tid & 63;
  int wv = tid >> 6;                                    // wave 0..3
  int tokBase = blockIdx.x * 64 + wv * 16;
  int row = lane & 15, kg = lane >> 4;                  // A: M-row, k-group
  const float* xr = x + (size_t)(tokBase + row) * Dq + kg * 8;
  const bf16x8* Bh = (const bf16x8*)Wbh;
  const bf16x8* Bl = (const bf16x8*)Wbl;
  f32x4 acc0 = {0.f, 0.f, 0.f, 0.f};
  f32x4 acc1 = {0.f, 0.f, 0.f, 0.f};
  f32x4 acc2 = {0.f, 0.f, 0.f, 0.f};

  float4 c0 = *(const float4*)(xr);                     // prefetch k-step 0
  float4 c1 = *(const float4*)(xr + 4);
  for (int ks = 0; ks < 24; ++ks) {
    float4 n0, n1;
    if (ks < 23) {                                      // prefetch next k-step
      n0 = *(const float4*)(xr + (ks + 1) * 32);
      n1 = *(const float4*)(xr + (ks + 1) * 32 + 4);
    }
    float fs0 = c0.x, fs1 = c0.y, fs2 = c0.z, fs3 = c0.w;
    float fs4 = c1.x, fs5 = c1.y, fs6 = c1.z, fs7 = c1.w;
    bf16x8 ah, al;
#define SPLIT(J, V) { unsigned u = __float_as_uint(V); \
    unsigned short h = (unsigned short)(u >> 16); \
    float hr = __uint_as_float((unsigned)h << 16); \
    float rr = (V) - hr; \
    ah[J] = (short)h; al[J] = (short)(__float_as_uint(rr) >> 16); }
    SPLIT(0, fs0) SPLIT(1, fs1) SPLIT(2, fs2) SPLIT(3, fs3)
    SPLIT(4, fs4) SPLIT(5, fs5) SPLIT(6, fs6) SPLIT(7, fs7)
#undef SPLIT
    int fi = (ks * 3) * 64 + lane;
    bf16x8 bh0 = Bh[fi], bh1 = Bh[fi + 64], bh2 = Bh[fi + 128];
    bf16x8 bl0 = Bl[fi], bl1 = Bl[fi + 64], bl2 = Bl[fi + 128];
    acc0 = __builtin_amdgcn_mfma_f32_16x16x32_bf16(al, bh0, acc0, 0, 0, 0);
    acc1 = __builtin_amdgcn_mfma_f32_16x16x32_bf16(al, bh1, acc1, 0, 0, 0);
    acc2 = __builtin_amdgcn_mfma_f32_16x16x32_bf16(al, bh2, acc2, 0, 0, 0);
    acc0 = __builtin_amdgcn_mfma_f32_16x16x32_bf16(ah, bl0, acc0, 0, 0, 0);
    acc1 = __builtin_amdgcn_mfma_f32_16x16x32_bf16(ah, bl1, acc1, 0, 0, 0);
    acc2 = __builtin_amdgcn_mfma_f32_16x16x32_bf16(ah, bl2, acc2, 0, 0, 0);
    acc0 = __builtin_amdgcn_mfma_f32_16x16x32_bf16(ah, bh0, acc0, 0, 0, 0);
    acc1 = __builtin_amdgcn_mfma_f32_16x16x32_bf16(ah, bh1, acc1, 0, 0, 0);
    acc2 = __builtin_amdgcn_mfma_f32_16x16x32_bf16(ah, bh2, acc2, 0, 0, 0);
    c0 = n0; c1 = n1;
  }
  // C/D: col = lane&15 (class within tile), row = kg*4 + reg (token)  [m89]
  int colc = lane & 15;
#pragma unroll
  for (int r = 0; r < 4; ++r) {
    size_t tok = (size_t)tokBase + kg * 4 + r;
    em[tok * Cq + colc]      = acc0[r] + bias[colc];
    em[tok * Cq + 16 + colc] = acc1[r] + bias[16 + colc];
    if (colc < 5)
      em[tok * Cq + 32 + colc] = acc2[r] + bias[32 + colc];
  }
}

// ---------------- Kernel 2: serial CRF (R11/R12 pk-packed; unchanged) ----------------
__global__ __launch_bounds__(256) void crf_serial_kernel(
    const float* __restrict__ em, const float* __restrict__ startv,
    const float* __restrict__ endv, const float* __restrict__ trans,
    const int* __restrict__ labels, const unsigned char* __restrict__ maskb,
    float* __restrict__ vhist, float* __restrict__ llp,
    int* __restrict__ lenp, int* __restrict__ lastp)
{
  __shared__ float semm[(Sq + 4) * Cq];    // 516 rows: 4 pad rows kill clamps
  __shared__ float sexch[128];
  __shared__ float s_score, s_logZ;
  int b = blockIdx.x;
  int tid = threadIdx.x, wid = tid >> 6, lane = tid & 63;
  int cl = lane < Cq ? lane : Cq - 1;

  int esz4 = (maskb[1] == 0) ? 1 : 0;
  int len = 0;
#pragma unroll
  for (int k = 0; k < 8; ++k) {
    size_t t = (size_t)lane + (size_t)k * 64;
    unsigned char mb = esz4 ? maskb[((size_t)b * Sq + t) * 4] : maskb[(size_t)b * Sq + t];
    len += (mb != 0);
  }
#pragma unroll
  for (int off = 32; off; off >>= 1) len += __shfl_xor(len, off);

  const float4* src4 = (const float4*)(em + (size_t)b * Sq * Cq);
  float4* dst4 = (float4*)semm;
  for (int i = tid; i < (Sq * Cq) / 4; i += 256) dst4[i] = src4[i];
  if (tid < 4 * Cq) semm[Sq * Cq + tid] = 0.f;
  __syncthreads();

  const float L2E = 1.4426950408889634f, LN2 = 0.6931471805599453f;

  if (wid == 0) {
    // ---- forward, exp domain; 18 pk_fma + 1 fma per step ----
    f32x2 E2[18];
#pragma unroll
    for (int i = 0; i < 18; ++i) {
      E2[i].x = exp2f(trans[(2 * i) * Cq + cl] * L2E);
      E2[i].y = exp2f(trans[(2 * i + 1) * Cq + cl] * L2E);
    }
    float E36 = exp2f(trans[36 * Cq + cl] * L2E);
    float* sE = sexch;
    const float4* se4 = (const float4*)sE;
    float a0 = (lane < Cq) ? (startv[cl] + semm[cl]) : -3.0e38f;
    float K0 = bcast(a0, 0);
    float ez = (lane < Cq) ? exp2f((a0 - K0) * L2E) : 0.f;
    int eacc = 0;
    float wA = exp2f(semm[1 * Cq + cl] * L2E), wB = exp2f(semm[2 * Cq + cl] * L2E);
    float wC = exp2f(semm[3 * Cq + cl] * L2E), wD = exp2f(semm[4 * Cq + cl] * L2E);
    for (int t = 1; t < len; ++t) {
      sE[lane] = ez;                                    // ds_write (in-order DS)
      float raw = semm[(t + 4) * Cq + cl];              // pad rows: no clamp
      float4 gv[10];
#pragma unroll
      for (int q = 0; q < 10; ++q) gv[q] = se4[q];      // 10x ds_read_b128 bcast
      int e0 = ((__float_as_int(gv[0].x) >> 23) & 255) - 127;
      float scale = __int_as_float((127 - e0) << 23);   // 2^-e0 exact
      f32x2 sa = {0.f, 0.f}, sb = {0.f, 0.f};
#define FPK(i) { f32x2 g; \
      if ((i) & 1) { g.x = gv[(i) >> 1].z; g.y = gv[(i) >> 1].w; } \
      else         { g.x = gv[(i) >> 1].x; g.y = gv[(i) >> 1].y; } \
      if ((i) & 1) sb = pk_fma(g, E2[i], sb); else sa = pk_fma(g, E2[i], sa); }
      REP18(FPK)
#undef FPK
      float dot = ((sa.x + sb.x) + (sa.y + sb.y)) + gv[9].x * E36;
      float wcur = wA; wA = wB; wB = wC; wC = wD;
      ez = dot * (wcur * scale);
      eacc += e0;
      wD = exp2f(raw * L2E);
    }
    float xv = (lane < Cq) ? LN2 * (log2f(ez) + (float)eacc) + K0 + endv[cl] : -3.0e38f;
    float mm = xv;
#pragma unroll
    for (int off = 32; off; off >>= 1) mm = fmaxf(mm, __shfl_xor(mm, off));
    float es = exp2f((xv - mm) * L2E);
#pragma unroll
    for (int off = 32; off; off >>= 1) es += __shfl_xor(es, off);
    if (lane == 0) s_logZ = mm + log2f(es) * LN2;
  } else if (wid == 1) {
    // ---- viterbi: pk_add (exact) + max3 nests (exact) -> tags identical ----
    f32x2 T2[18];
#pragma unroll
    for (int i = 0; i < 18; ++i) {
      T2[i].x = trans[(2 * i) * Cq + cl];
      T2[i].y = trans[(2 * i + 1) * Cq + cl];
    }
    float T36 = trans[36 * Cq + cl];
    float* sV = sexch + 64;
    const float4* sv4 = (const float4*)sV;
    float v = (lane < Cq) ? (startv[cl] + semm[cl]) : -3.0e38f;
    if (lane < Cq) vhist[((size_t)b * Sq) * VST + cl] = v;
    float emA = semm[1 * Cq + cl], emB = semm[2 * Cq + cl];
    float emC = semm[3 * Cq + cl], emD = semm[4 * Cq + cl];
    for (int t = 1; t < len; ++t) {
      sV[lane] = v;
      float raw = semm[(t + 4) * Cq + cl];
      float4 gv[10];
#pragma unroll
      for (int q = 0; q < 10; ++q) gv[q] = sv4[q];
      float m0 = -3.0e38f, m1 = -3.0e38f, m2 = -3.0e38f, m3 = -3.0e38f;
#define VPK(i) { f32x2 g; \
      if ((i) & 1) { g.x = gv[(i) >> 1].z; g.y = gv[(i) >> 1].w; } \
      else         { g.x = gv[(i) >> 1].x; g.y = gv[(i) >> 1].y; } \
      f32x2 c = pk_add(g, T2[i]); \
      if (((i) & 3) == 0) m0 = fmaxf(fmaxf(m0, c.x), c.y); \
      else if (((i) & 3) == 1) m1 = fmaxf(fmaxf(m1, c.x), c.y); \
      else if (((i) & 3) == 2) m2 = fmaxf(fmaxf(m2, c.x), c.y); \
      else m3 = fmaxf(fmaxf(m3, c.x), c.y); }
      REP18(VPK)
#undef VPK
      float c36 = gv[9].x + T36;
      float best = fmaxf(fmaxf(fmaxf(m0, m1), fmaxf(m2, m3)), c36);
      float emc = emA; emA = emB; emB = emC; emC = emD;
      v = (lane < Cq) ? best + emc : -3.0e38f;
      if (lane < Cq) vhist[((size_t)b * Sq + t) * VST + cl] = v;
      emD = raw;
    }
    float xv = (lane < Cq) ? v + endv[cl] : -3.0e38f;
    int idx = (lane < Cq) ? lane : 1000;
#pragma unroll
    for (int off = 32; off; off >>= 1) {
      float xo = __shfl_xor(xv, off); int io = __shfl_xor(idx, off);
      if (xo > xv || (xo == xv && io < idx)) { xv = xo; idx = io; }
    }
    if (lane == 0) { lastp[b] = idx; lenp[b] = len; }
  } else if (wid == 2) {
    // ---- gold path score ----
    const int* lab = labels + (size_t)b * Sq;
    float sc = 0.f;
#pragma unroll
    for (int k = 0; k < 8; ++k) {
      int t = 1 + lane + k * 64;
      if (t < len) {
        int lp = lab[t - 1], lt = lab[t];
        sc += trans[lp * Cq + lt] + semm[t * Cq + lt];
      }
    }
#pragma unroll
    for (int off = 32; off; off >>= 1) sc += __shfl_xor(sc, off);
    if (lane == 0) {
      int l0 = lab[0], lf = lab[len - 1];
      s_score = sc + startv[l0] + semm[l0] + endv[lf];
    }
  }
  __syncthreads();
  if (tid == 0) llp[b] = s_score - s_logZ;
}

// ---------------- Kernel 3: backpointers (parallel recompute) ----------------
__global__ __launch_bounds__(256) void crf_bp_kernel(
    const float* __restrict__ vhist, const float* __restrict__ trans,
    const int* __restrict__ lenp, unsigned char* __restrict__ bp)
{
  int b = blockIdx.x >> 2, chunk = blockIdx.x & 3;
  int wid = threadIdx.x >> 6, lane = threadIdx.x & 63;
  int cl = lane < Cq ? lane : Cq - 1;
  int len = lenp[b];
#define DECLT(i) float T##i = trans[(i) * Cq + cl];
  REP37(DECLT)
  int tend = 1 + (chunk + 1) * 128; if (tend > len) tend = len;
  int rl9 = lane < VST ? lane : VST - 1;
  for (int t = 1 + chunk * 128 + wid; t < tend; t += 4) {
    float vr = vhist[((size_t)b * Sq + (t - 1)) * VST + rl9];
#define BCASTB(i) float br##i = bcast(vr, (i));
    REP37(BCASTB)
    float best = -3.0e38f; int bi = 0;
#define BARG(i) { float cnd = br##i + T##i; if (cnd > best) { best = cnd; bi = (i); } }
    REP37(BARG)                             // ascending + strict '>' => first-index tie-break
    if (lane < Cq) bp[((size_t)b * VST + cl) * Sq + t] = (unsigned char)bi;
  }
}

// ---------------- Kernel 4: register-resident backtrack ----------------
__global__ __launch_bounds__(64) void crf_back_kernel(
    const unsigned char* __restrict__ bp, const int* __restrict__ lenp,
    const int* __restrict__ lastp, float* __restrict__ outp)
{
  int b = blockIdx.x, lane = threadIdx.x;
  int len = __builtin_amdgcn_readfirstlane(lenp[b]);
  int tag = __builtin_amdgcn_readfirstlane(lastp[b]);
  int row = lane < VST ? lane : VST - 1;
  const uint4* src = (const uint4*)(bp + ((size_t)b * VST + row) * Sq);
  unsigned r[128];
#pragma unroll
  for (int k = 0; k < 32; ++k) {
    uint4 q = src[k];
    r[4 * k] = q.x; r[4 * k + 1] = q.y; r[4 * k + 2] = q.z; r[4 * k + 3] = q.w;
  }
  unsigned vt[8];
#pragma unroll
  for (int j = 0; j < 8; ++j) vt[j] = 0u;
  vt[7] = (lane == 63) ? (unsigned)tag : vt[7];
#pragma unroll
  for (int t = 510; t >= 0; --t) {
    int word = __builtin_amdgcn_readlane((int)r[(t + 1) >> 2], tag);
    int nt = (word >> (((t + 1) & 3) * 8)) & 0xff;
    tag = (t + 1 < len) ? nt : tag;
    vt[t >> 6] = (lane == (t & 63)) ? (unsigned)tag : vt[t >> 6];
  }
#pragma unroll
  for (int j = 0; j < 8; ++j) {
    int t = j * 64 + lane;
    float o = (t < len) ? (float)(int)vt[j] : 36.0f;
    outp[(size_t)b * Sq + t] = o;
  }
}

// ---------------- Kernel 5: reduce ll partials ----------------
__global__ __launch_bounds__(64) void ll_reduce_kernel(
    const float* __restrict__ llp, float* __restrict__ outp)
{
  int lane = threadIdx.x;
  float s = llp[lane] + llp[lane + 64];
#pragma unroll
  for (int off = 32; off; off >>= 1) s += __shfl_xor(s, off);
  if (lane == 0) outp[0] = s;
}

extern "C" void kernel_launch(void* const* d_in, const int* in_sizes, int n_in,
                              void* d_out, int out_size, void* d_ws, size_t ws_size,
                              hipStream_t stream)
{
  const float* x      = (const float*)d_in[0];
  const float* W      = (const float*)d_in[1];
  const float* bias   = (const float*)d_in[2];
  const float* startv = (const float*)d_in[3];
  const float* endv   = (const float*)d_in[4];
  const float* trans  = (const float*)d_in[5];
  const int*   labels = (const int*)d_in[6];
  const unsigned char* maskb = (const unsigned char*)d_in[7];
  float* out = (float*)d_out;

  char* ws = (char*)d_ws;
  float* em            = (float*)(ws);                    // 9,699,328 B
  float* vhist         = (float*)(ws + 9699328);          // 10,485,760 B
  unsigned char* bpbuf = (unsigned char*)(ws + 20185088); // 2,621,440 B
  float* llp           = (float*)(ws + 22806528);
  int*   lenp          = (int*)(ws + 22807552);
  int*   lastp         = (int*)(ws + 22808064);
  unsigned short* Wbh  = (unsigned short*)(ws + 22808576); // 73,728 B
  unsigned short* Wbl  = (unsigned short*)(ws + 22882304); // 73,728 B

  prep_kernel<<<144, 256, 0, stream>>>(W, Wbh, Wbl);
  emis_kernel<<<1024, 256, 0, stream>>>(x, Wbh, Wbl, bias, em);
  crf_serial_kernel<<<128, 256, 0, stream>>>(em, startv, endv, trans, labels, maskb,
                                             vhist, llp, lenp, lastp);
  crf_bp_kernel<<<512, 256, 0, stream>>>(vhist, trans, lenp, bpbuf);
  crf_back_kernel<<<128, 64, 0, stream>>>(bpbuf, lenp, lastp, out + 1);
  ll_reduce_kernel<<<1, 64, 0, stream>>>(llp, out);
}